// Round 2
// baseline (387.027 us; speedup 1.0000x reference)
//
#include <hip/hip_runtime.h>

// LocalSorterModel collapsed:
//   out[b,r] = sum_{n,d} E[b,n,d] * W[r,n,d] + const[r]
//   W[r,n,d] = sum_k CA[r,n,k]*pw_w[k,d] + CB[r,n,k]*pw_w[k,DIM+d]
//   CA[r,n,k] = sum_{p:I_p=n} cls_w[r,p*DIM+k]   (4 terms)
//   CB[r,n,k] = sum_{p:J_p=n} cls_w[r,p*DIM+k]   (4 terms)
//   const[r]  = cls_b[r] + sum_k pw_b[k]*sum_n CA[r,n,k]
//
// ws layout (floats):
//   C2  [600][2048]   row rn = n*120+r; k2<1024 -> CA, k2>=1024 -> CB
//   WT  [5120][128]   WT[(n*1024+d)*128 + r], cols 120..127 zero padding
//   constv [120]

#define NITEMS 5
#define NR     120
#define NRP    128
#define DIMK   1024
#define MF     600     // 5*120 fold rows
#define KF     2048    // fold K
#define KX     5120    // main K (5*1024)
#define BATCH  2048

__global__ __launch_bounds__(256) void k_prep(const float* __restrict__ cls_w,
                                              float* __restrict__ C2) {
    int tid = blockIdx.x * 256 + threadIdx.x;     // 600*2048 total
    if (tid >= MF * KF) return;
    int k2  = tid & (KF - 1);
    int row = tid >> 11;          // n*120 + r
    int n = row / NR;
    int r = row % NR;
    const float* base = cls_w + r * (20 * DIMK);
    float v = 0.f;
    if (k2 < DIMK) {
        // CA: pairs p = 4n+q, q=0..3  (IDX_I[p] = p/4 = n)
        int k = k2;
        #pragma unroll
        for (int q = 0; q < 4; q++) v += base[(4 * n + q) * DIMK + k];
    } else {
        // CB: for each i != n, p = 4i + (n>i ? n-1 : n)  (IDX_J[p] = n)
        int k = k2 - DIMK;
        #pragma unroll
        for (int i = 0; i < NITEMS; i++) {
            if (i == n) continue;
            int q = (n > i) ? (n - 1) : n;
            v += base[(4 * i + q) * DIMK + k];
        }
    }
    C2[tid] = v;
}

__global__ __launch_bounds__(256) void k_zero(float* __restrict__ WT) {
    int tid = blockIdx.x * 256 + threadIdx.x;     // 640*256 = 163840 float4s
    reinterpret_cast<float4*>(WT)[tid] = make_float4(0.f, 0.f, 0.f, 0.f);
}

__global__ __launch_bounds__(256) void k_const(const float* __restrict__ C2,
                                               const float* __restrict__ pw_b,
                                               const float* __restrict__ cls_b,
                                               float* __restrict__ constv) {
    int r = blockIdx.x;
    int t = threadIdx.x;
    float acc = 0.f;
    for (int n = 0; n < NITEMS; n++) {
        const float* rowp = C2 + (size_t)(n * NR + r) * KF;   // CA half (k<1024)
        for (int k = t; k < DIMK; k += 256) acc += rowp[k] * pw_b[k];
    }
    __shared__ float red[256];
    red[t] = acc;
    __syncthreads();
    for (int s = 128; s > 0; s >>= 1) {
        if (t < s) red[t] += red[t + s];
        __syncthreads();
    }
    if (t == 0) constv[r] = cls_b[r] + red[0];
}

__global__ __launch_bounds__(256) void k_initout(const float* __restrict__ constv,
                                                 float* __restrict__ out) {
    int tid = blockIdx.x * 256 + threadIdx.x;     // 2048*120
    if (tid < BATCH * NR) out[tid] = constv[tid % NR];
}

// fold GEMM: A = C2 [600][2048], B[k2][d] = pw_w[(k2&1023)*2048 + (k2>>10)*1024 + d]
// C: WT[(n*1024+d)*128 + r] += ..., row rn = n*120+r
// grid (8 d-tiles, 5 m-tiles, 8 k-splits of 256)
__global__ __launch_bounds__(256) void k_fold(const float* __restrict__ C2,
                                              const float* __restrict__ pw_w,
                                              float* __restrict__ WT) {
    __shared__ float As[8][128];
    __shared__ float Bs[8][128];
    const int d0  = blockIdx.x * 128;
    const int m0  = blockIdx.y * 128;
    const int kc0 = blockIdx.z * 256;
    const int t = threadIdx.x;
    const int tx = t & 15, ty = t >> 4;

    float acc[8][8];
    #pragma unroll
    for (int i = 0; i < 8; i++)
        #pragma unroll
        for (int j = 0; j < 8; j++) acc[i][j] = 0.f;

    const int arow = t >> 1, ak = (t & 1) * 4;
    const int bk = t >> 5, bd = (t & 31) * 4;

    for (int kt = 0; kt < 256; kt += 8) {
        const int kbase = kc0 + kt;
        float4 av;
        const int grow = m0 + arow;
        if (grow < MF)
            av = *reinterpret_cast<const float4*>(C2 + (size_t)grow * KF + kbase + ak);
        else
            av = make_float4(0.f, 0.f, 0.f, 0.f);
        As[ak + 0][arow] = av.x; As[ak + 1][arow] = av.y;
        As[ak + 2][arow] = av.z; As[ak + 3][arow] = av.w;

        const int k2 = kbase + bk;
        const float* bsrc = pw_w + (size_t)(k2 & (DIMK - 1)) * 2048 + (k2 >> 10) * DIMK + d0 + bd;
        *reinterpret_cast<float4*>(&Bs[bk][bd]) = *reinterpret_cast<const float4*>(bsrc);
        __syncthreads();

        #pragma unroll
        for (int kk = 0; kk < 8; kk++) {
            float a0[4], a1[4], b0[4], b1[4];
            *(float4*)a0 = *(const float4*)&As[kk][ty * 4];
            *(float4*)a1 = *(const float4*)&As[kk][64 + ty * 4];
            *(float4*)b0 = *(const float4*)&Bs[kk][tx * 4];
            *(float4*)b1 = *(const float4*)&Bs[kk][64 + tx * 4];
            #pragma unroll
            for (int i = 0; i < 4; i++)
                #pragma unroll
                for (int j = 0; j < 4; j++) {
                    acc[i][j]         += a0[i] * b0[j];
                    acc[i][j + 4]     += a0[i] * b1[j];
                    acc[i + 4][j]     += a1[i] * b0[j];
                    acc[i + 4][j + 4] += a1[i] * b1[j];
                }
        }
        __syncthreads();
    }

    #pragma unroll
    for (int i = 0; i < 8; i++) {
        const int lrow = (i < 4) ? (ty * 4 + i) : (64 + ty * 4 + (i - 4));
        const int grow = m0 + lrow;
        if (grow >= MF) continue;
        const int n = grow / NR, r = grow % NR;
        #pragma unroll
        for (int j = 0; j < 8; j++) {
            const int ld = (j < 4) ? (tx * 4 + j) : (64 + tx * 4 + (j - 4));
            const int x = n * DIMK + d0 + ld;
            atomicAdd(&WT[(size_t)x * NRP + r], acc[i][j]);
        }
    }
}

// main GEMM: A = E [2048][5120], B = WT [5120][128], out[b*120+r] += (cols<120)
// grid (16 m-tiles of 128, 32 k-splits of 160) = 512 blocks (2 per CU)
__global__ __launch_bounds__(256) void k_main(const float* __restrict__ E,
                                              const float* __restrict__ WT,
                                              float* __restrict__ out) {
    __shared__ float As[8][128];
    __shared__ float Bs[8][128];
    const int m0  = blockIdx.x * 128;
    const int kc0 = blockIdx.y * 160;
    const int t = threadIdx.x;
    const int tx = t & 15, ty = t >> 4;

    float acc[8][8];
    #pragma unroll
    for (int i = 0; i < 8; i++)
        #pragma unroll
        for (int j = 0; j < 8; j++) acc[i][j] = 0.f;

    const int arow = t >> 1, ak = (t & 1) * 4;
    const int bk = t >> 5, bd = (t & 31) * 4;

    for (int kt = 0; kt < 160; kt += 8) {
        const int kbase = kc0 + kt;
        float4 av = *reinterpret_cast<const float4*>(E + (size_t)(m0 + arow) * KX + kbase + ak);
        As[ak + 0][arow] = av.x; As[ak + 1][arow] = av.y;
        As[ak + 2][arow] = av.z; As[ak + 3][arow] = av.w;

        *reinterpret_cast<float4*>(&Bs[bk][bd]) =
            *reinterpret_cast<const float4*>(WT + (size_t)(kbase + bk) * NRP + bd);
        __syncthreads();

        #pragma unroll
        for (int kk = 0; kk < 8; kk++) {
            float a0[4], a1[4], b0[4], b1[4];
            *(float4*)a0 = *(const float4*)&As[kk][ty * 4];
            *(float4*)a1 = *(const float4*)&As[kk][64 + ty * 4];
            *(float4*)b0 = *(const float4*)&Bs[kk][tx * 4];
            *(float4*)b1 = *(const float4*)&Bs[kk][64 + tx * 4];
            #pragma unroll
            for (int i = 0; i < 4; i++)
                #pragma unroll
                for (int j = 0; j < 4; j++) {
                    acc[i][j]         += a0[i] * b0[j];
                    acc[i][j + 4]     += a0[i] * b1[j];
                    acc[i + 4][j]     += a1[i] * b0[j];
                    acc[i + 4][j + 4] += a1[i] * b1[j];
                }
        }
        __syncthreads();
    }

    #pragma unroll
    for (int i = 0; i < 8; i++) {
        const int lrow = (i < 4) ? (ty * 4 + i) : (64 + ty * 4 + (i - 4));
        const int b = m0 + lrow;
        #pragma unroll
        for (int j = 0; j < 8; j++) {
            const int col = (j < 4) ? (tx * 4 + j) : (64 + tx * 4 + (j - 4));
            if (col < NR) atomicAdd(&out[(size_t)b * NR + col], acc[i][j]);
        }
    }
}

extern "C" void kernel_launch(void* const* d_in, const int* in_sizes, int n_in,
                              void* d_out, int out_size, void* d_ws, size_t ws_size,
                              hipStream_t stream) {
    const float* embeds = (const float*)d_in[0];  // [2048][5][1024]
    const float* pw_w   = (const float*)d_in[1];  // [1024][2048]
    const float* pw_b   = (const float*)d_in[2];  // [1024]
    const float* cls_w  = (const float*)d_in[3];  // [120][20480]
    const float* cls_b  = (const float*)d_in[4];  // [120]
    float* out = (float*)d_out;                   // [2048][120]

    float* C2     = (float*)d_ws;                         // 600*2048
    float* WT     = C2 + (size_t)MF * KF;                 // 5120*128
    float* constv = WT + (size_t)KX * NRP;                // 120

    k_prep<<<dim3((MF * KF + 255) / 256), dim3(256), 0, stream>>>(cls_w, C2);
    k_zero<<<dim3((KX * NRP) / 1024), dim3(256), 0, stream>>>(WT);
    k_const<<<dim3(NR), dim3(256), 0, stream>>>(C2, pw_b, cls_b, constv);
    k_fold<<<dim3(8, 5, 8), dim3(256), 0, stream>>>(C2, pw_w, WT);
    k_initout<<<dim3((BATCH * NR + 255) / 256), dim3(256), 0, stream>>>(constv, out);
    k_main<<<dim3(16, 32), dim3(256), 0, stream>>>(embeds, WT, out);
}

// Round 3
// 194.186 us; speedup vs baseline: 1.9931x; 1.9931x over previous
//
#include <hip/hip_runtime.h>

// LocalSorterModel collapsed:
//   out[b,r] = sum_x E[b,x] * WT[x,r] + const[r],  x = n*1024+d  (K = 5120)
//   WT[(n*1024+d)*128+r] = sum_k2 Bmat[k2][d] * C2T[k2][n*128+r]
//     Bmat[k2][d] = pw_w[(k2&1023)*2048 + (k2>>10)*1024 + d]   (w1|w2 halves)
//     C2T[k2][n*128+r] = CA[r,n,k2] (k2<1024) or CB[r,n,k2-1024]
//   const[r] = cls_b[r] + sum_k pw_b[k] * sum_n CA[r,n,k]
// All GEMMs atomic-free: K-split partials + reduce kernels.

#define NR 120
#define KX 5120
#define C2T_W 640                   // 5*128 (r 120..127 zero-padded)
#define C2T_FLOATS (2048*640)
#define WT_FLOATS (5120*128)
#define PF_SLICE 655360             // 5*1024*128 per fold k-split
#define PM_SLICE 262144             // 2048*128 per main k-split

// ---- C2T build: gather-sum from cls_w with LDS transpose ----
// grid (16 k-tiles of 64, 5 n, 8 = half*4 + rtile)
__global__ __launch_bounds__(256) void k_prep(const float* __restrict__ cls_w,
                                              float* __restrict__ C2T) {
    __shared__ float T[32][65];
    const int t = threadIdx.x;
    const int k0 = blockIdx.x * 64;
    const int n = blockIdx.y;
    const int half = blockIdx.z >> 2;
    const int r0 = (blockIdx.z & 3) * 32;
    #pragma unroll
    for (int e = 0; e < 8; e++) {
        int idx = e * 256 + t;
        int lr = idx >> 6, lk = idx & 63;
        int r = r0 + lr, k = k0 + lk;
        float v = 0.f;
        if (r < NR) {
            const float* base = cls_w + (size_t)r * 20480 + k;
            if (half == 0) {
                #pragma unroll
                for (int q = 0; q < 4; q++) v += base[(4 * n + q) * 1024];
            } else {
                #pragma unroll
                for (int i = 0; i < 5; i++) {
                    if (i == n) continue;
                    int q = (n > i) ? (n - 1) : n;
                    v += base[(4 * i + q) * 1024];
                }
            }
        }
        T[lr][lk] = v;
    }
    __syncthreads();
    #pragma unroll
    for (int e = 0; e < 8; e++) {
        int lk = e * 8 + (t >> 5);
        int lr = t & 31;
        C2T[(size_t)(half * 1024 + k0 + lk) * C2T_W + n * 128 + r0 + lr] = T[lr][lk];
    }
}

__global__ __launch_bounds__(256) void k_const(const float* __restrict__ C2T,
                                               const float* __restrict__ pw_b,
                                               const float* __restrict__ cls_b,
                                               float* __restrict__ constv) {
    const int r = blockIdx.x;
    const int t = threadIdx.x;
    float acc = 0.f;
    for (int k = t; k < 1024; k += 256) {
        float pb = pw_b[k];
        const float* c = C2T + (size_t)k * C2T_W + r;
        #pragma unroll
        for (int n = 0; n < 5; n++) acc += c[n * 128] * pb;
    }
    __shared__ float red[256];
    red[t] = acc;
    __syncthreads();
    for (int s = 128; s > 0; s >>= 1) {
        if (t < s) red[t] += red[t + s];
        __syncthreads();
    }
    if (t == 0) constv[r] = cls_b[r] + red[0];
}

// ---- fold GEMM: rows = d (64/block), cols = r (128), K over k2 ----
// grid (16 d-tiles, 5 n, nksf k-splits); Pf[ks][(n*1024+d)*128+r]
__global__ __launch_bounds__(256) void k_fold(const float* __restrict__ pw_w,
                                              const float* __restrict__ C2T,
                                              float* __restrict__ Pf,
                                              int kchunk) {
    __shared__ float As[8][64];
    __shared__ float Bs[8][128];
    const int t = threadIdx.x;
    const int d0 = blockIdx.x * 64;
    const int n = blockIdx.y;
    const int kc0 = blockIdx.z * kchunk;
    const int tx = t & 15, ty = t >> 4;
    const int aak = t >> 4, aad = (t & 15) * 4;       // t<128: A stage
    const int bk = t >> 5, bd = (t & 31) * 4;

    float acc[4][8];
    #pragma unroll
    for (int i = 0; i < 4; i++)
        #pragma unroll
        for (int j = 0; j < 8; j++) acc[i][j] = 0.f;

    float4 av, bv;
    {
        int k2 = kc0 + aak;
        if (t < 128)
            av = *(const float4*)(pw_w + (size_t)(k2 & 1023) * 2048 + (k2 >> 10) * 1024 + d0 + aad);
        bv = *(const float4*)(C2T + (size_t)(kc0 + bk) * C2T_W + n * 128 + bd);
    }
    const int niter = kchunk >> 3;
    for (int kt = 0; kt < niter; kt++) {
        if (kt) __syncthreads();
        if (t < 128) *(float4*)&As[aak][aad] = av;
        *(float4*)&Bs[bk][bd] = bv;
        __syncthreads();
        if (kt + 1 < niter) {
            int kb = kc0 + (kt + 1) * 8;
            int k2 = kb + aak;
            if (t < 128)
                av = *(const float4*)(pw_w + (size_t)(k2 & 1023) * 2048 + (k2 >> 10) * 1024 + d0 + aad);
            bv = *(const float4*)(C2T + (size_t)(kb + bk) * C2T_W + n * 128 + bd);
        }
        #pragma unroll
        for (int kk = 0; kk < 8; kk++) {
            float a[4], b0[4], b1[4];
            *(float4*)a  = *(const float4*)&As[kk][ty * 4];
            *(float4*)b0 = *(const float4*)&Bs[kk][tx * 4];
            *(float4*)b1 = *(const float4*)&Bs[kk][64 + tx * 4];
            #pragma unroll
            for (int i = 0; i < 4; i++)
                #pragma unroll
                for (int j = 0; j < 4; j++) {
                    acc[i][j]     += a[i] * b0[j];
                    acc[i][j + 4] += a[i] * b1[j];
                }
        }
    }
    float* dst = Pf + (size_t)blockIdx.z * PF_SLICE + ((size_t)n * 1024 + d0) * 128;
    #pragma unroll
    for (int i = 0; i < 4; i++) {
        int row = ty * 4 + i;
        *(float4*)(dst + (size_t)row * 128 + tx * 4) =
            make_float4(acc[i][0], acc[i][1], acc[i][2], acc[i][3]);
        *(float4*)(dst + (size_t)row * 128 + 64 + tx * 4) =
            make_float4(acc[i][4], acc[i][5], acc[i][6], acc[i][7]);
    }
}

__global__ __launch_bounds__(256) void k_foldred(const float* __restrict__ Pf,
                                                 float* __restrict__ WT, int nksf) {
    int i4 = blockIdx.x * 256 + threadIdx.x;       // 163840 float4s
    const float4* p = (const float4*)Pf;
    float4 s = p[i4];
    for (int ks = 1; ks < nksf; ks++) {
        float4 v = p[(size_t)ks * (PF_SLICE / 4) + i4];
        s.x += v.x; s.y += v.y; s.z += v.z; s.w += v.w;
    }
    ((float4*)WT)[i4] = s;
}

// ---- main GEMM: rows = b (64/block), cols = r (128), K = 5120 split ----
// grid (32 m-tiles, nksm); Pm[ks][b*128+r]
__global__ __launch_bounds__(256) void k_main(const float* __restrict__ E,
                                              const float* __restrict__ WT,
                                              float* __restrict__ Pm,
                                              int kchunk) {
    __shared__ float As[8][64];
    __shared__ float Bs[8][128];
    const int t = threadIdx.x;
    const int m0 = blockIdx.x * 64;
    const int kc0 = blockIdx.y * kchunk;
    const int tx = t & 15, ty = t >> 4;
    const int arow = t >> 1, ak = (t & 1) * 4;     // t<128: A stage
    const int bk = t >> 5, bd = (t & 31) * 4;

    float acc[4][8];
    #pragma unroll
    for (int i = 0; i < 4; i++)
        #pragma unroll
        for (int j = 0; j < 8; j++) acc[i][j] = 0.f;

    float4 av, bv;
    if (t < 128) av = *(const float4*)(E + (size_t)(m0 + arow) * KX + kc0 + ak);
    bv = *(const float4*)(WT + (size_t)(kc0 + bk) * 128 + bd);

    const int niter = kchunk >> 3;
    for (int kt = 0; kt < niter; kt++) {
        if (kt) __syncthreads();
        if (t < 128) {
            As[ak + 0][arow] = av.x; As[ak + 1][arow] = av.y;
            As[ak + 2][arow] = av.z; As[ak + 3][arow] = av.w;
        }
        *(float4*)&Bs[bk][bd] = bv;
        __syncthreads();
        if (kt + 1 < niter) {
            int kb = kc0 + (kt + 1) * 8;
            if (t < 128) av = *(const float4*)(E + (size_t)(m0 + arow) * KX + kb + ak);
            bv = *(const float4*)(WT + (size_t)(kb + bk) * 128 + bd);
        }
        #pragma unroll
        for (int kk = 0; kk < 8; kk++) {
            float a[4], b0[4], b1[4];
            *(float4*)a  = *(const float4*)&As[kk][ty * 4];
            *(float4*)b0 = *(const float4*)&Bs[kk][tx * 4];
            *(float4*)b1 = *(const float4*)&Bs[kk][64 + tx * 4];
            #pragma unroll
            for (int i = 0; i < 4; i++)
                #pragma unroll
                for (int j = 0; j < 4; j++) {
                    acc[i][j]     += a[i] * b0[j];
                    acc[i][j + 4] += a[i] * b1[j];
                }
        }
    }
    float* dst = Pm + (size_t)blockIdx.y * PM_SLICE + (size_t)m0 * 128;
    #pragma unroll
    for (int i = 0; i < 4; i++) {
        int row = ty * 4 + i;
        *(float4*)(dst + (size_t)row * 128 + tx * 4) =
            make_float4(acc[i][0], acc[i][1], acc[i][2], acc[i][3]);
        *(float4*)(dst + (size_t)row * 128 + 64 + tx * 4) =
            make_float4(acc[i][4], acc[i][5], acc[i][6], acc[i][7]);
    }
}

__global__ __launch_bounds__(256) void k_mainred(const float* __restrict__ Pm,
                                                 const float* __restrict__ constv,
                                                 float* __restrict__ out, int nksm) {
    int tid = blockIdx.x * 256 + threadIdx.x;      // 2048*120
    int b = tid / NR, r = tid - b * NR;
    float s = constv[r];
    for (int ks = 0; ks < nksm; ks++) s += Pm[(size_t)ks * PM_SLICE + b * 128 + r];
    out[tid] = s;
}

extern "C" void kernel_launch(void* const* d_in, const int* in_sizes, int n_in,
                              void* d_out, int out_size, void* d_ws, size_t ws_size,
                              hipStream_t stream) {
    const float* embeds = (const float*)d_in[0];
    const float* pw_w   = (const float*)d_in[1];
    const float* pw_b   = (const float*)d_in[2];
    const float* cls_w  = (const float*)d_in[3];
    const float* cls_b  = (const float*)d_in[4];
    float* out = (float*)d_out;

    float* C2T    = (float*)d_ws;
    float* WT     = C2T + C2T_FLOATS;
    float* constv = WT + WT_FLOATS;
    float* scratch = constv + 128;                 // Pf then (aliased) Pm

    size_t wsf = ws_size / 4;
    size_t base = (size_t)C2T_FLOATS + WT_FLOATS + 128;
    size_t avail = (wsf > base) ? (wsf - base) : 0;
    int nksm = 32;
    while (nksm > 4 && (size_t)nksm * PM_SLICE > avail) nksm >>= 1;
    int nksf = 8;
    while (nksf > 2 && (size_t)nksf * PF_SLICE > avail) nksf >>= 1;

    k_prep<<<dim3(16, 5, 8), dim3(256), 0, stream>>>(cls_w, C2T);
    k_const<<<dim3(NR), dim3(256), 0, stream>>>(C2T, pw_b, cls_b, constv);
    k_fold<<<dim3(16, 5, nksf), dim3(256), 0, stream>>>(pw_w, C2T, scratch, 2048 / nksf);
    k_foldred<<<dim3(640), dim3(256), 0, stream>>>(scratch, WT, nksf);
    k_main<<<dim3(32, nksm), dim3(256), 0, stream>>>(embeds, WT, scratch, KX / nksm);
    k_mainred<<<dim3(960), dim3(256), 0, stream>>>(scratch, constv, out, nksm);
}